// Round 6
// baseline (477.559 us; speedup 1.0000x reference)
//
#include <hip/hip_runtime.h>

#define N_NODES 100000
#define N_EDGES 3200000
#define IN_CH 512
#define HID 16
#define OUT_CH 64

#define SCAN_BS 256
#define SCAN_CHUNK 1024                                   // 4 elements per thread
#define SCAN_NB ((N_NODES + SCAN_CHUNK - 1) / SCAN_CHUNK) // 98 (must be <= 128)

#define N_XCD 8
#define RANGE (N_NODES / N_XCD)          // 12500 nodes per range

// binning / scatter geometry
#define BIN_BS 256
#define BIN_GRID 2048
#define BIN_ROUNDS ((N_EDGES / 4 + BIN_GRID * BIN_BS - 1) / (BIN_GRID * BIN_BS))  // 2
#define SC_BS 256
#define SC_BLOCKS_PER_GRP 256
#define SC_GRID (N_XCD * SC_BLOCKS_PER_GRP)

typedef int v4i __attribute__((ext_vector_type(4)));
typedef int v2i __attribute__((ext_vector_type(2)));

// ---------------- degree count (single pass, unranged) ----------------

__global__ void k_init_deg(int* deg) {
    int i = blockIdx.x * blockDim.x + threadIdx.x;
    if (i < N_NODES) deg[i] = 1;  // self-loop
}

__global__ void k_count(const int* __restrict__ dst, int* __restrict__ deg) {
    const v4i* d4 = (const v4i*)dst;
    for (int i = blockIdx.x * blockDim.x + threadIdx.x; i < N_EDGES / 4;
         i += gridDim.x * blockDim.x) {
        v4i v = __builtin_nontemporal_load(d4 + i);
        atomicAdd(&deg[v.x], 1);
        atomicAdd(&deg[v.y], 1);
        atomicAdd(&deg[v.z], 1);
        atomicAdd(&deg[v.w], 1);
    }
}

// ---------------- scan ----------------

__global__ void k_scan_partial(const int* __restrict__ deg, int* __restrict__ partials) {
    __shared__ int sm[SCAN_BS];
    int tid = threadIdx.x;
    int base = blockIdx.x * SCAN_CHUNK;
    int s = 0;
    for (int j = 0; j < 4; ++j) {
        int i = base + j * SCAN_BS + tid;
        if (i < N_NODES) s += deg[i] - 1;   // edge count (excl self-loop)
    }
    sm[tid] = s;
    __syncthreads();
    for (int st = SCAN_BS / 2; st > 0; st >>= 1) {
        if (tid < st) sm[tid] += sm[tid + st];
        __syncthreads();
    }
    if (tid == 0) partials[blockIdx.x] = sm[0];
}

__global__ void k_scan_offsets(int* partials) {  // 1 block, 128 threads
    __shared__ int sm[128];
    int tid = threadIdx.x;
    int v = (tid < SCAN_NB) ? partials[tid] : 0;
    sm[tid] = v;
    __syncthreads();
    for (int st = 1; st < 128; st <<= 1) {
        int t = (tid >= st) ? sm[tid - st] : 0;
        __syncthreads();
        sm[tid] += t;
        __syncthreads();
    }
    if (tid < SCAN_NB) partials[tid] = sm[tid] - v;  // exclusive
}

__global__ void k_scan_final(const int* __restrict__ deg, const int* __restrict__ partials,
                             int* __restrict__ off, int* __restrict__ cur,
                             float* __restrict__ dinv) {
    __shared__ int sm[SCAN_BS];
    int tid = threadIdx.x;
    int base = blockIdx.x * SCAN_CHUNK + tid * 4;
    int v[4];
    int s = 0;
    for (int j = 0; j < 4; ++j) {
        int i = base + j;
        v[j] = (i < N_NODES) ? deg[i] - 1 : 0;
        s += v[j];
    }
    sm[tid] = s;
    __syncthreads();
    for (int st = 1; st < SCAN_BS; st <<= 1) {
        int t = (tid >= st) ? sm[tid - st] : 0;
        __syncthreads();
        sm[tid] += t;
        __syncthreads();
    }
    int run = partials[blockIdx.x] + sm[tid] - s;  // exclusive global prefix
    for (int j = 0; j < 4; ++j) {
        int i = base + j;
        if (i < N_NODES) {
            off[i] = run;
            cur[i] = run;
            dinv[i] = rsqrtf((float)deg[i]);
        }
        run += v[j];
    }
}

__global__ void k_init_bcur(const int* __restrict__ off, int* __restrict__ bcur) {
    int t = threadIdx.x;  // 8 threads
    if (t < N_XCD) bcur[t] = off[t * RANGE];
}

// ---------------- Phase A: bin (src,dst) pairs by dst range ----------------
// Bucket g occupies pairs[off[g*RANGE] .. off[(g+1)*RANGE]) — exact sizes from scan.

__global__ __launch_bounds__(BIN_BS) void k_bin(const int* __restrict__ src,
                                                const int* __restrict__ dst,
                                                v2i* __restrict__ pairs,
                                                int* __restrict__ bcur) {
    __shared__ int cnt[N_XCD];
    __shared__ int base[N_XCD];
    const v4i* d4 = (const v4i*)dst;
    const v4i* s4 = (const v4i*)src;
    const int tid = threadIdx.x;
    const int nq = N_EDGES / 4;

    for (int r = 0; r < BIN_ROUNDS; ++r) {
        int i = (r * BIN_GRID + blockIdx.x) * BIN_BS + tid;
        bool valid = (i < nq);
        if (tid < N_XCD) cnt[tid] = 0;
        __syncthreads();
        v4i dv, sv;
        int b[4], rank[4];
        if (valid) {
            dv = __builtin_nontemporal_load(d4 + i);
            sv = __builtin_nontemporal_load(s4 + i);
            b[0] = dv.x / RANGE; rank[0] = atomicAdd(&cnt[b[0]], 1);
            b[1] = dv.y / RANGE; rank[1] = atomicAdd(&cnt[b[1]], 1);
            b[2] = dv.z / RANGE; rank[2] = atomicAdd(&cnt[b[2]], 1);
            b[3] = dv.w / RANGE; rank[3] = atomicAdd(&cnt[b[3]], 1);
        }
        __syncthreads();
        if (tid < N_XCD) base[tid] = atomicAdd(&bcur[tid], cnt[tid]);
        __syncthreads();
        if (valid) {
            v2i p0 = {sv.x, dv.x}; pairs[base[b[0]] + rank[0]] = p0;
            v2i p1 = {sv.y, dv.y}; pairs[base[b[1]] + rank[1]] = p1;
            v2i p2 = {sv.z, dv.z}; pairs[base[b[2]] + rank[2]] = p2;
            v2i p3 = {sv.w, dv.w}; pairs[base[b[3]] + rank[3]] = p3;
        }
    }
}

// ---------------- Phase B: scatter within XCD-local bucket ----------------
// Group g reads only its ~3.2MB pair slice; csr window (~1.6MB) + cur slice
// (50KB) are the only write-side working set — fits any single L2.

__global__ __launch_bounds__(SC_BS) void k_scatter(const v2i* __restrict__ pairs,
                                                   const int* __restrict__ off,
                                                   int* __restrict__ cur,
                                                   int* __restrict__ csr) {
    const int grp = blockIdx.x & (N_XCD - 1);
    const int blk = blockIdx.x >> 3;
    const int lo = off[grp * RANGE];
    const int hi = (grp == N_XCD - 1) ? N_EDGES : off[(grp + 1) * RANGE];
    for (int i = lo + blk * SC_BS + threadIdx.x; i < hi;
         i += SC_BLOCKS_PER_GRP * SC_BS) {
        v2i e = __builtin_nontemporal_load(pairs + i);
        int p = atomicAdd(&cur[e.y], 1);
        csr[p] = e.x;
    }
}

// ---------------- GEMM1: y1 = (x @ W1) * dinv[n] ----------------

#define G1_BS 256
#define G1_NODES 128
#define G1_KT 64
#define G1_STRIDE (G1_KT + 4)   // 68 floats: 2-way bank access (free)

__global__ __launch_bounds__(G1_BS) void k_gemm1(const float* __restrict__ x,
                                                 const float* __restrict__ W1,
                                                 const float* __restrict__ dinv,
                                                 float* __restrict__ y1) {
    __shared__ float xt[G1_NODES * G1_STRIDE];  // 34816 B
    __shared__ float wt[G1_KT * HID];           // 4096 B
    const int tid = threadIdx.x;
    const int nl = tid >> 2;   // node slot 0..63
    const int cg = tid & 3;    // channel group (4 ch each)
    const int node_base = blockIdx.x * G1_NODES;

    float4 acc0 = {0.f, 0.f, 0.f, 0.f};
    float4 acc1 = {0.f, 0.f, 0.f, 0.f};

    for (int kt = 0; kt < IN_CH; kt += G1_KT) {
        __syncthreads();
        for (int j = 0; j < 8; ++j) {
            int f4 = j * G1_BS + tid;
            int r = f4 >> 4;
            int c4 = f4 & 15;
            int gr = node_base + r;
            float4 v = {0.f, 0.f, 0.f, 0.f};
            if (gr < N_NODES)
                v = *(const float4*)(x + (size_t)gr * IN_CH + kt + c4 * 4);
            *(float4*)(xt + r * G1_STRIDE + c4 * 4) = v;
        }
        {
            int r = tid >> 2;
            int c4 = tid & 3;
            *(float4*)(wt + r * HID + c4 * 4) =
                *(const float4*)(W1 + (size_t)(kt + r) * HID + c4 * 4);
        }
        __syncthreads();

        for (int kk = 0; kk < G1_KT; ++kk) {
            float xv0 = xt[nl * G1_STRIDE + kk];
            float xv1 = xt[(nl + 64) * G1_STRIDE + kk];
            float4 w = *(const float4*)(wt + kk * HID + cg * 4);
            acc0.x += xv0 * w.x; acc0.y += xv0 * w.y;
            acc0.z += xv0 * w.z; acc0.w += xv0 * w.w;
            acc1.x += xv1 * w.x; acc1.y += xv1 * w.y;
            acc1.z += xv1 * w.z; acc1.w += xv1 * w.w;
        }
    }

    int n0 = node_base + nl;
    int n1 = n0 + 64;
    if (n0 < N_NODES) {
        float dv = dinv[n0];
        float4 o = {acc0.x * dv, acc0.y * dv, acc0.z * dv, acc0.w * dv};
        *(float4*)(y1 + (size_t)n0 * HID + cg * 4) = o;
    }
    if (n1 < N_NODES) {
        float dv = dinv[n1];
        float4 o = {acc1.x * dv, acc1.y * dv, acc1.z * dv, acc1.w * dv};
        *(float4*)(y1 + (size_t)n1 * HID + cg * 4) = o;
    }
}

// ---------------- layer1 aggregation ----------------

__global__ void k_layer1(const float* __restrict__ y1, const int* __restrict__ off,
                         const int* __restrict__ deg, const int* __restrict__ csr,
                         const float* __restrict__ dinv, const float* __restrict__ b1,
                         float* __restrict__ y2) {
    int t = blockIdx.x * blockDim.x + threadIdx.x;  // grid exactly N_NODES*16
    int n = t >> 4;
    int c = t & 15;
    int base = off[n];
    int cnt = deg[n] - 1;
    float a0 = 0.f, a1 = 0.f, a2 = 0.f, a3 = 0.f;
    int p = 0;
    for (; p + 4 <= cnt; p += 4) {
        int s0 = csr[base + p + 0];
        int s1 = csr[base + p + 1];
        int s2 = csr[base + p + 2];
        int s3 = csr[base + p + 3];
        a0 += y1[s0 * HID + c];
        a1 += y1[s1 * HID + c];
        a2 += y1[s2 * HID + c];
        a3 += y1[s3 * HID + c];
    }
    for (; p < cnt; ++p) a0 += y1[csr[base + p] * HID + c];
    float acc = (a0 + a1) + (a2 + a3);
    float dv = dinv[n];
    float h = dv * (acc + y1[n * HID + c]) + b1[c];
    h = fmaxf(h, 0.f);
    y2[n * HID + c] = h * dv;
}

// ---------------- layer2 aggregation fused with GEMM2 + bias ----------------

__global__ void k_layer2(const float* __restrict__ y2, const int* __restrict__ off,
                         const int* __restrict__ deg, const int* __restrict__ csr,
                         const float* __restrict__ dinv, const float* __restrict__ W2,
                         const float* __restrict__ b2, float* __restrict__ out) {
    __shared__ float w2[HID * OUT_CH];  // 4 KB
    __shared__ float bs[OUT_CH];
    int tid = threadIdx.x;
    for (int j = tid; j < HID * OUT_CH; j += blockDim.x) w2[j] = W2[j];
    if (tid < OUT_CH) bs[tid] = b2[tid];
    __syncthreads();

    int t = blockIdx.x * blockDim.x + tid;  // grid exactly N_NODES*16
    int n = t >> 4;
    int c = t & 15;
    int base = off[n];
    int cnt = deg[n] - 1;
    float a0 = 0.f, a1 = 0.f, a2 = 0.f, a3 = 0.f;
    int p = 0;
    for (; p + 4 <= cnt; p += 4) {
        int s0 = csr[base + p + 0];
        int s1 = csr[base + p + 1];
        int s2 = csr[base + p + 2];
        int s3 = csr[base + p + 3];
        a0 += y2[s0 * HID + c];
        a1 += y2[s1 * HID + c];
        a2 += y2[s2 * HID + c];
        a3 += y2[s3 * HID + c];
    }
    for (; p < cnt; ++p) a0 += y2[csr[base + p] * HID + c];
    float acc = (a0 + a1) + (a2 + a3);
    float z = dinv[n] * (acc + y2[n * HID + c]);  // this lane's channel of agg

    float4 o = {bs[c * 4 + 0], bs[c * 4 + 1], bs[c * 4 + 2], bs[c * 4 + 3]};
    int lane = tid & 63;
    int gsub = lane >> 4;  // which 16-lane node-group within the wave
    for (int cc = 0; cc < HID; ++cc) {
        float zz = __shfl(z, gsub * 16 + cc, 64);
        float4 w = *(const float4*)(w2 + cc * OUT_CH + c * 4);
        o.x += zz * w.x; o.y += zz * w.y; o.z += zz * w.z; o.w += zz * w.w;
    }
    *(float4*)(out + (size_t)n * OUT_CH + c * 4) = o;
}

// ---------------- launch ----------------

extern "C" void kernel_launch(void* const* d_in, const int* in_sizes, int n_in,
                              void* d_out, int out_size, void* d_ws, size_t ws_size,
                              hipStream_t stream) {
    const float* x  = (const float*)d_in[0];
    const int*   ei = (const int*)d_in[1];
    const float* W1 = (const float*)d_in[2];
    const float* b1 = (const float*)d_in[3];
    const float* W2 = (const float*)d_in[4];
    const float* b2 = (const float*)d_in[5];
    float* out = (float*)d_out;

    const int* src = ei;            // edge_index[0]
    const int* dst = ei + N_EDGES;  // edge_index[1]

    char* w = (char*)d_ws;
    const size_t SN = 409600;  // per-N-array slot
    int*   deg      = (int*)(w);
    float* dinv     = (float*)(w + SN);
    int*   off      = (int*)(w + 2 * SN);
    int*   cur      = (int*)(w + 3 * SN);
    int*   partials = (int*)(w + 4 * SN);
    int*   bcur     = (int*)(w + 4 * SN + 4096);
    int*   csr      = (int*)(w + 5 * SN);                 // 12.8 MB
    // region B (25.6MB): pairs during bin/scatter, then y1/y2 (pairs dead
    // before gemm1 writes y1 — no temporal overlap).
    char*  regB     = w + 5 * SN + 13107200;
    v2i*   pairs    = (v2i*)regB;                         // 25.6 MB
    float* y1       = (float*)regB;                       // 6.4 MB
    float* y2       = (float*)(regB + 6553600);           // 6.4 MB
    // total ws use: ~40.4 MB

    k_init_deg<<<(N_NODES + 255) / 256, 256, 0, stream>>>(deg);
    k_count<<<2048, 256, 0, stream>>>(dst, deg);
    k_scan_partial<<<SCAN_NB, SCAN_BS, 0, stream>>>(deg, partials);
    k_scan_offsets<<<1, 128, 0, stream>>>(partials);
    k_scan_final<<<SCAN_NB, SCAN_BS, 0, stream>>>(deg, partials, off, cur, dinv);
    k_init_bcur<<<1, 64, 0, stream>>>(off, bcur);
    k_bin<<<BIN_GRID, BIN_BS, 0, stream>>>(src, dst, pairs, bcur);
    k_scatter<<<SC_GRID, SC_BS, 0, stream>>>(pairs, off, cur, csr);
    k_gemm1<<<(N_NODES + G1_NODES - 1) / G1_NODES, G1_BS, 0, stream>>>(x, W1, dinv, y1);
    k_layer1<<<(N_NODES * HID) / 256, 256, 0, stream>>>(y1, off, deg, csr, dinv, b1, y2);
    k_layer2<<<(N_NODES * HID) / 256, 256, 0, stream>>>(y2, off, deg, csr, dinv, W2, b2, out);
}

// Round 7
// 251.485 us; speedup vs baseline: 1.8990x; 1.8990x over previous
//
#include <hip/hip_runtime.h>

#define N_NODES 100000
#define N_EDGES 3200000
#define IN_CH 512
#define HID 16
#define OUT_CH 64

#define SCAN_BS 256
#define SCAN_CHUNK 1024                                   // 4 elements per thread
#define SCAN_NB ((N_NODES + SCAN_CHUNK - 1) / SCAN_CHUNK) // 98 (must be <= 128)

// ---- hierarchical counting-sort geometry ----
// L1: 98 buckets x 1024 nodes (bucket = dst>>10), cap mean+11.4sigma
// L2: 16 leaves/bucket x 64 nodes, cap mean+11.3sigma
#define NB1 98
#define CAP1 34816
#define LEAF 64
#define CAP2 2560
#define NLEAF 1563                 // ceil(100000/64); leaf id == pairs2 slot
#define NLEAF_SLOTS (NB1 * 16)     // 1568 allocated slots
#define BIN1_CHUNK 4096
#define BIN1_BLOCKS ((N_EDGES + BIN1_CHUNK - 1) / BIN1_CHUNK)  // 782
#define BIN2_SPLIT 9
#define BIN2_CHUNK 3872            // 9*3872 >= CAP1

// ---------------- init ----------------

__global__ void k_init_bcur(int* bcur1, int* bcur2) {
    int i = blockIdx.x * blockDim.x + threadIdx.x;
    if (i < NB1) bcur1[i] = i * CAP1;
    if (i < NLEAF_SLOTS) bcur2[i] = i * CAP2;
}

// ---------------- L1 bin: 98 buckets, packed (src<<10)|local ----------------

__global__ __launch_bounds__(256) void k_bin1(const int* __restrict__ src,
                                              const int* __restrict__ dst,
                                              int* __restrict__ pairs1,
                                              int* __restrict__ bcur1) {
    __shared__ int cnt[NB1];
    __shared__ int base[NB1];
    const int tid = threadIdx.x;
    const int lo = blockIdx.x * BIN1_CHUNK;
    const int hi = min(lo + BIN1_CHUNK, N_EDGES);
    if (tid < NB1) cnt[tid] = 0;
    __syncthreads();
    for (int i = lo + tid; i < hi; i += 256) {
        int d = __builtin_nontemporal_load(dst + i);
        atomicAdd(&cnt[d >> 10], 1);
    }
    __syncthreads();
    if (tid < NB1 && cnt[tid] > 0) base[tid] = atomicAdd(&bcur1[tid], cnt[tid]);
    __syncthreads();
    if (tid < NB1) cnt[tid] = 0;
    __syncthreads();
    for (int i = lo + tid; i < hi; i += 256) {
        int d = __builtin_nontemporal_load(dst + i);
        int s = __builtin_nontemporal_load(src + i);
        int b = d >> 10;
        int r = atomicAdd(&cnt[b], 1);
        pairs1[base[b] + r] = (s << 10) | (d & 1023);
    }
}

// ---------------- L2 bin: 16 leaves within each bucket ----------------

__global__ __launch_bounds__(256) void k_bin2(const int* __restrict__ pairs1,
                                              const int* __restrict__ bcur1,
                                              int* __restrict__ pairs2,
                                              int* __restrict__ bcur2) {
    __shared__ int cnt[16];
    __shared__ int base[16];
    const int b = blockIdx.x / BIN2_SPLIT;
    const int s = blockIdx.x % BIN2_SPLIT;
    const int tid = threadIdx.x;
    const int len = bcur1[b] - b * CAP1;
    const int lo = b * CAP1 + min(s * BIN2_CHUNK, len);
    const int hi = b * CAP1 + min((s + 1) * BIN2_CHUNK, len);
    if (tid < 16) cnt[tid] = 0;
    __syncthreads();
    for (int i = lo + tid; i < hi; i += 256)
        atomicAdd(&cnt[(pairs1[i] & 1023) >> 6], 1);
    __syncthreads();
    if (tid < 16 && cnt[tid] > 0) base[tid] = atomicAdd(&bcur2[b * 16 + tid], cnt[tid]);
    __syncthreads();
    if (tid < 16) cnt[tid] = 0;
    __syncthreads();
    for (int i = lo + tid; i < hi; i += 256) {
        int e = pairs1[i];
        int l = (e & 1023) >> 6;
        int r = atomicAdd(&cnt[l], 1);
        pairs2[base[l] + r] = e;
    }
}

// ---------------- per-leaf degree count (replaces global-atomic k_count) ----

__global__ __launch_bounds__(256) void k_leafcount(const int* __restrict__ pairs2,
                                                   const int* __restrict__ bcur2,
                                                   int* __restrict__ deg) {
    __shared__ int cnt[LEAF];
    const int leaf = blockIdx.x;
    const int tid = threadIdx.x;
    const int base2 = leaf * CAP2;
    const int len = min(bcur2[leaf] - base2, CAP2);
    if (tid < LEAF) cnt[tid] = 0;
    __syncthreads();
    for (int i = tid; i < len; i += 256)
        atomicAdd(&cnt[pairs2[base2 + i] & 63], 1);
    __syncthreads();
    int node = leaf * LEAF + tid;
    if (tid < LEAF && node < N_NODES) deg[node] = 1 + cnt[tid];  // +1 self-loop
}

// ---------------- scan ----------------

__global__ void k_scan_partial(const int* __restrict__ deg, int* __restrict__ partials) {
    __shared__ int sm[SCAN_BS];
    int tid = threadIdx.x;
    int base = blockIdx.x * SCAN_CHUNK;
    int s = 0;
    for (int j = 0; j < 4; ++j) {
        int i = base + j * SCAN_BS + tid;
        if (i < N_NODES) s += deg[i] - 1;   // edge count (excl self-loop)
    }
    sm[tid] = s;
    __syncthreads();
    for (int st = SCAN_BS / 2; st > 0; st >>= 1) {
        if (tid < st) sm[tid] += sm[tid + st];
        __syncthreads();
    }
    if (tid == 0) partials[blockIdx.x] = sm[0];
}

__global__ void k_scan_offsets(int* partials) {  // 1 block, 128 threads
    __shared__ int sm[128];
    int tid = threadIdx.x;
    int v = (tid < SCAN_NB) ? partials[tid] : 0;
    sm[tid] = v;
    __syncthreads();
    for (int st = 1; st < 128; st <<= 1) {
        int t = (tid >= st) ? sm[tid - st] : 0;
        __syncthreads();
        sm[tid] += t;
        __syncthreads();
    }
    if (tid < SCAN_NB) partials[tid] = sm[tid] - v;  // exclusive
}

__global__ void k_scan_final(const int* __restrict__ deg, const int* __restrict__ partials,
                             int* __restrict__ off, float* __restrict__ dinv) {
    __shared__ int sm[SCAN_BS];
    int tid = threadIdx.x;
    int base = blockIdx.x * SCAN_CHUNK + tid * 4;
    int v[4];
    int s = 0;
    for (int j = 0; j < 4; ++j) {
        int i = base + j;
        v[j] = (i < N_NODES) ? deg[i] - 1 : 0;
        s += v[j];
    }
    sm[tid] = s;
    __syncthreads();
    for (int st = 1; st < SCAN_BS; st <<= 1) {
        int t = (tid >= st) ? sm[tid - st] : 0;
        __syncthreads();
        sm[tid] += t;
        __syncthreads();
    }
    int run = partials[blockIdx.x] + sm[tid] - s;  // exclusive global prefix
    for (int j = 0; j < 4; ++j) {
        int i = base + j;
        if (i < N_NODES) {
            off[i] = run;
            dinv[i] = rsqrtf((float)deg[i]);
        }
        run += v[j];
    }
}

// ---------------- per-leaf scatter: LDS place + coalesced global write ------

__global__ __launch_bounds__(256) void k_scatter2(const int* __restrict__ pairs2,
                                                  const int* __restrict__ bcur2,
                                                  const int* __restrict__ off,
                                                  int* __restrict__ csr) {
    __shared__ int lcur[LEAF];
    __shared__ int buf[CAP2];
    const int leaf = blockIdx.x;
    const int tid = threadIdx.x;
    const int nbase = leaf * LEAF;
    const int obase = off[nbase];
    const int base2 = leaf * CAP2;
    const int len = min(bcur2[leaf] - base2, CAP2);
    if (tid < LEAF) {
        int node = nbase + tid;
        lcur[tid] = (node < N_NODES ? off[node] : 0) - obase;
    }
    __syncthreads();
    for (int i = tid; i < len; i += 256) {
        int e = pairs2[base2 + i];
        int p = atomicAdd(&lcur[e & 63], 1);   // LDS atomic, block-local
        buf[p] = e >> 10;                      // src id
    }
    __syncthreads();
    for (int i = tid; i < len; i += 256)
        csr[obase + i] = buf[i];               // fully coalesced lines
}

// ---------------- GEMM1: y1 = (x @ W1) * dinv[n] ----------------

#define G1_BS 256
#define G1_NODES 128
#define G1_KT 64
#define G1_STRIDE (G1_KT + 4)   // 68 floats: 2-way bank access (free)

__global__ __launch_bounds__(G1_BS) void k_gemm1(const float* __restrict__ x,
                                                 const float* __restrict__ W1,
                                                 const float* __restrict__ dinv,
                                                 float* __restrict__ y1) {
    __shared__ float xt[G1_NODES * G1_STRIDE];  // 34816 B
    __shared__ float wt[G1_KT * HID];           // 4096 B
    const int tid = threadIdx.x;
    const int nl = tid >> 2;   // node slot 0..63
    const int cg = tid & 3;    // channel group (4 ch each)
    const int node_base = blockIdx.x * G1_NODES;

    float4 acc0 = {0.f, 0.f, 0.f, 0.f};
    float4 acc1 = {0.f, 0.f, 0.f, 0.f};

    for (int kt = 0; kt < IN_CH; kt += G1_KT) {
        __syncthreads();
        for (int j = 0; j < 8; ++j) {
            int f4 = j * G1_BS + tid;
            int r = f4 >> 4;
            int c4 = f4 & 15;
            int gr = node_base + r;
            float4 v = {0.f, 0.f, 0.f, 0.f};
            if (gr < N_NODES)
                v = *(const float4*)(x + (size_t)gr * IN_CH + kt + c4 * 4);
            *(float4*)(xt + r * G1_STRIDE + c4 * 4) = v;
        }
        {
            int r = tid >> 2;
            int c4 = tid & 3;
            *(float4*)(wt + r * HID + c4 * 4) =
                *(const float4*)(W1 + (size_t)(kt + r) * HID + c4 * 4);
        }
        __syncthreads();

        for (int kk = 0; kk < G1_KT; ++kk) {
            float xv0 = xt[nl * G1_STRIDE + kk];
            float xv1 = xt[(nl + 64) * G1_STRIDE + kk];
            float4 w = *(const float4*)(wt + kk * HID + cg * 4);
            acc0.x += xv0 * w.x; acc0.y += xv0 * w.y;
            acc0.z += xv0 * w.z; acc0.w += xv0 * w.w;
            acc1.x += xv1 * w.x; acc1.y += xv1 * w.y;
            acc1.z += xv1 * w.z; acc1.w += xv1 * w.w;
        }
    }

    int n0 = node_base + nl;
    int n1 = n0 + 64;
    if (n0 < N_NODES) {
        float dv = dinv[n0];
        float4 o = {acc0.x * dv, acc0.y * dv, acc0.z * dv, acc0.w * dv};
        *(float4*)(y1 + (size_t)n0 * HID + cg * 4) = o;
    }
    if (n1 < N_NODES) {
        float dv = dinv[n1];
        float4 o = {acc1.x * dv, acc1.y * dv, acc1.z * dv, acc1.w * dv};
        *(float4*)(y1 + (size_t)n1 * HID + cg * 4) = o;
    }
}

// ---------------- layer1 aggregation ----------------

__global__ void k_layer1(const float* __restrict__ y1, const int* __restrict__ off,
                         const int* __restrict__ deg, const int* __restrict__ csr,
                         const float* __restrict__ dinv, const float* __restrict__ b1,
                         float* __restrict__ y2) {
    int t = blockIdx.x * blockDim.x + threadIdx.x;  // grid exactly N_NODES*16
    int n = t >> 4;
    int c = t & 15;
    int base = off[n];
    int cnt = deg[n] - 1;
    float a0 = 0.f, a1 = 0.f, a2 = 0.f, a3 = 0.f;
    int p = 0;
    for (; p + 4 <= cnt; p += 4) {
        int s0 = csr[base + p + 0];
        int s1 = csr[base + p + 1];
        int s2 = csr[base + p + 2];
        int s3 = csr[base + p + 3];
        a0 += y1[s0 * HID + c];
        a1 += y1[s1 * HID + c];
        a2 += y1[s2 * HID + c];
        a3 += y1[s3 * HID + c];
    }
    for (; p < cnt; ++p) a0 += y1[csr[base + p] * HID + c];
    float acc = (a0 + a1) + (a2 + a3);
    float dv = dinv[n];
    float h = dv * (acc + y1[n * HID + c]) + b1[c];
    h = fmaxf(h, 0.f);
    y2[n * HID + c] = h * dv;
}

// ---------------- layer2 aggregation fused with GEMM2 + bias ----------------

__global__ void k_layer2(const float* __restrict__ y2, const int* __restrict__ off,
                         const int* __restrict__ deg, const int* __restrict__ csr,
                         const float* __restrict__ dinv, const float* __restrict__ W2,
                         const float* __restrict__ b2, float* __restrict__ out) {
    __shared__ float w2[HID * OUT_CH];  // 4 KB
    __shared__ float bs[OUT_CH];
    int tid = threadIdx.x;
    for (int j = tid; j < HID * OUT_CH; j += blockDim.x) w2[j] = W2[j];
    if (tid < OUT_CH) bs[tid] = b2[tid];
    __syncthreads();

    int t = blockIdx.x * blockDim.x + tid;  // grid exactly N_NODES*16
    int n = t >> 4;
    int c = t & 15;
    int base = off[n];
    int cnt = deg[n] - 1;
    float a0 = 0.f, a1 = 0.f, a2 = 0.f, a3 = 0.f;
    int p = 0;
    for (; p + 4 <= cnt; p += 4) {
        int s0 = csr[base + p + 0];
        int s1 = csr[base + p + 1];
        int s2 = csr[base + p + 2];
        int s3 = csr[base + p + 3];
        a0 += y2[s0 * HID + c];
        a1 += y2[s1 * HID + c];
        a2 += y2[s2 * HID + c];
        a3 += y2[s3 * HID + c];
    }
    for (; p < cnt; ++p) a0 += y2[csr[base + p] * HID + c];
    float acc = (a0 + a1) + (a2 + a3);
    float z = dinv[n] * (acc + y2[n * HID + c]);  // this lane's channel of agg

    float4 o = {bs[c * 4 + 0], bs[c * 4 + 1], bs[c * 4 + 2], bs[c * 4 + 3]};
    int lane = tid & 63;
    int gsub = lane >> 4;  // which 16-lane node-group within the wave
    for (int cc = 0; cc < HID; ++cc) {
        float zz = __shfl(z, gsub * 16 + cc, 64);
        float4 w = *(const float4*)(w2 + cc * OUT_CH + c * 4);
        o.x += zz * w.x; o.y += zz * w.y; o.z += zz * w.z; o.w += zz * w.w;
    }
    *(float4*)(out + (size_t)n * OUT_CH + c * 4) = o;
}

// ---------------- launch ----------------

extern "C" void kernel_launch(void* const* d_in, const int* in_sizes, int n_in,
                              void* d_out, int out_size, void* d_ws, size_t ws_size,
                              hipStream_t stream) {
    const float* x  = (const float*)d_in[0];
    const int*   ei = (const int*)d_in[1];
    const float* W1 = (const float*)d_in[2];
    const float* b1 = (const float*)d_in[3];
    const float* W2 = (const float*)d_in[4];
    const float* b2 = (const float*)d_in[5];
    float* out = (float*)d_out;

    const int* src = ei;            // edge_index[0]
    const int* dst = ei + N_EDGES;  // edge_index[1]

    char* w = (char*)d_ws;
    const size_t SN = 409600;  // per-N-array slot
    int*   deg      = (int*)(w);
    float* dinv     = (float*)(w + SN);
    int*   off      = (int*)(w + 2 * SN);
    int*   partials = (int*)(w + 3 * SN);               // 4 KB
    int*   bcur1    = (int*)(w + 3 * SN + 8192);        // 392 B
    int*   bcur2    = (int*)(w + 3 * SN + 16384);       // 6.3 KB
    // regB: pairs1 (13.65 MB) during binning, then csr (12.8 MB)
    char*  regB     = w + 4 * SN;
    int*   pairs1   = (int*)regB;
    int*   csr      = (int*)regB;                       // overlay: pairs1 dead after bin2
    // regC: pairs2 (16.06 MB) during sort, then y1/y2 (12.8 MB)
    char*  regC     = regB + (size_t)NB1 * CAP1 * 4;
    int*   pairs2   = (int*)regC;
    float* y1       = (float*)regC;                     // overlay: pairs2 dead after scatter2
    float* y2       = (float*)(regC + 6553600);
    // total ws use: ~31.4 MB

    k_init_bcur<<<(NLEAF_SLOTS + 255) / 256, 256, 0, stream>>>(bcur1, bcur2);
    k_bin1<<<BIN1_BLOCKS, 256, 0, stream>>>(src, dst, pairs1, bcur1);
    k_bin2<<<NB1 * BIN2_SPLIT, 256, 0, stream>>>(pairs1, bcur1, pairs2, bcur2);
    k_leafcount<<<NLEAF, 256, 0, stream>>>(pairs2, bcur2, deg);
    k_scan_partial<<<SCAN_NB, SCAN_BS, 0, stream>>>(deg, partials);
    k_scan_offsets<<<1, 128, 0, stream>>>(partials);
    k_scan_final<<<SCAN_NB, SCAN_BS, 0, stream>>>(deg, partials, off, dinv);
    k_scatter2<<<NLEAF, 256, 0, stream>>>(pairs2, bcur2, off, csr);
    k_gemm1<<<(N_NODES + G1_NODES - 1) / G1_NODES, G1_BS, 0, stream>>>(x, W1, dinv, y1);
    k_layer1<<<(N_NODES * HID) / 256, 256, 0, stream>>>(y1, off, deg, csr, dinv, b1, y2);
    k_layer2<<<(N_NODES * HID) / 256, 256, 0, stream>>>(y2, off, deg, csr, dinv, W2, b2, out);
}

// Round 8
// 248.501 us; speedup vs baseline: 1.9218x; 1.0120x over previous
//
#include <hip/hip_runtime.h>

#define N_NODES 100000
#define N_EDGES 3200000
#define IN_CH 512
#define HID 16
#define OUT_CH 64

// ---- hierarchical counting-sort geometry ----
#define NB1 98
#define CAP1 34816
#define LEAF 64
#define CAP2 2560
#define NLEAF 1563                 // ceil(100000/64)
#define NLEAF_SLOTS (NB1 * 16)     // 1568 allocated slots
#define BIN1_CHUNK 4096
#define BIN1_BLOCKS ((N_EDGES + BIN1_CHUNK - 1) / BIN1_CHUNK)  // 782
#define BIN2_SPLIT 9
#define BIN2_CHUNK 3872            // 9*3872 >= CAP1

__device__ __forceinline__ float4 f4add(float4 a, float4 b) {
    return float4{a.x + b.x, a.y + b.y, a.z + b.z, a.w + b.w};
}
__device__ __forceinline__ float4 f4fma(float s, float4 w, float4 a) {
    return float4{a.x + s * w.x, a.y + s * w.y, a.z + s * w.z, a.w + s * w.w};
}

// ---------------- init ----------------

__global__ void k_init_bcur(int* bcur1, int* bcur2) {
    int i = blockIdx.x * blockDim.x + threadIdx.x;
    if (i < NB1) bcur1[i] = i * CAP1;
    if (i < NLEAF_SLOTS) bcur2[i] = i * CAP2;
}

// ---------------- L1 bin: 98 buckets, packed (src<<10)|local ----------------

__global__ __launch_bounds__(256) void k_bin1(const int* __restrict__ src,
                                              const int* __restrict__ dst,
                                              int* __restrict__ pairs1,
                                              int* __restrict__ bcur1) {
    __shared__ int cnt[NB1];
    __shared__ int base[NB1];
    const int tid = threadIdx.x;
    const int lo = blockIdx.x * BIN1_CHUNK;
    const int hi = min(lo + BIN1_CHUNK, N_EDGES);
    if (tid < NB1) cnt[tid] = 0;
    __syncthreads();
    for (int i = lo + tid; i < hi; i += 256) {
        int d = __builtin_nontemporal_load(dst + i);
        atomicAdd(&cnt[d >> 10], 1);
    }
    __syncthreads();
    if (tid < NB1 && cnt[tid] > 0) base[tid] = atomicAdd(&bcur1[tid], cnt[tid]);
    __syncthreads();
    if (tid < NB1) cnt[tid] = 0;
    __syncthreads();
    for (int i = lo + tid; i < hi; i += 256) {
        int d = __builtin_nontemporal_load(dst + i);
        int s = __builtin_nontemporal_load(src + i);
        int b = d >> 10;
        int r = atomicAdd(&cnt[b], 1);
        pairs1[base[b] + r] = (s << 10) | (d & 1023);
    }
}

// ---------------- L2 bin: 16 leaves within each bucket ----------------

__global__ __launch_bounds__(256) void k_bin2(const int* __restrict__ pairs1,
                                              const int* __restrict__ bcur1,
                                              int* __restrict__ pairs2,
                                              int* __restrict__ bcur2) {
    __shared__ int cnt[16];
    __shared__ int base[16];
    const int b = blockIdx.x / BIN2_SPLIT;
    const int s = blockIdx.x % BIN2_SPLIT;
    const int tid = threadIdx.x;
    const int len = bcur1[b] - b * CAP1;
    const int lo = b * CAP1 + min(s * BIN2_CHUNK, len);
    const int hi = b * CAP1 + min((s + 1) * BIN2_CHUNK, len);
    if (tid < 16) cnt[tid] = 0;
    __syncthreads();
    for (int i = lo + tid; i < hi; i += 256)
        atomicAdd(&cnt[(pairs1[i] & 1023) >> 6], 1);
    __syncthreads();
    if (tid < 16 && cnt[tid] > 0) base[tid] = atomicAdd(&bcur2[b * 16 + tid], cnt[tid]);
    __syncthreads();
    if (tid < 16) cnt[tid] = 0;
    __syncthreads();
    for (int i = lo + tid; i < hi; i += 256) {
        int e = pairs1[i];
        int l = (e & 1023) >> 6;
        int r = atomicAdd(&cnt[l], 1);
        pairs2[base[l] + r] = e;
    }
}

// ---------------- leaf-total exclusive scan (1 block) ----------------

__global__ __launch_bounds__(256) void k_leafscan(const int* __restrict__ bcur2,
                                                  int* __restrict__ leafoff) {
    __shared__ int sm[256];
    __shared__ int carry;
    const int tid = threadIdx.x;
    if (tid == 0) carry = 0;
    __syncthreads();
    for (int r = 0; r < (NLEAF_SLOTS + 255) / 256; ++r) {
        int idx = r * 256 + tid;
        int v = (idx < NLEAF_SLOTS) ? (bcur2[idx] - idx * CAP2) : 0;
        sm[tid] = v;
        __syncthreads();
        for (int st = 1; st < 256; st <<= 1) {
            int t = (tid >= st) ? sm[tid - st] : 0;
            __syncthreads();
            sm[tid] += t;
            __syncthreads();
        }
        if (idx < NLEAF_SLOTS) leafoff[idx] = carry + sm[tid] - v;  // exclusive
        int tot = sm[255];
        __syncthreads();
        if (tid == 0) carry += tot;
        __syncthreads();
    }
}

// ---------------- per-leaf: count + scan + scatter + off/deg/dinv -----------

__global__ __launch_bounds__(256) void k_scatter2(const int* __restrict__ pairs2,
                                                  const int* __restrict__ bcur2,
                                                  const int* __restrict__ leafoff,
                                                  int* __restrict__ off,
                                                  int* __restrict__ deg,
                                                  float* __restrict__ dinv,
                                                  int* __restrict__ csr) {
    __shared__ int cnt[LEAF];
    __shared__ int lcur[LEAF];
    __shared__ int buf[CAP2];
    const int leaf = blockIdx.x;
    const int tid = threadIdx.x;
    const int base2 = leaf * CAP2;
    const int len = min(bcur2[leaf] - base2, CAP2);
    const int obase = leafoff[leaf];
    if (tid < LEAF) cnt[tid] = 0;
    __syncthreads();
    for (int i = tid; i < len; i += 256)
        atomicAdd(&cnt[pairs2[base2 + i] & 63], 1);
    __syncthreads();
    if (tid < LEAF) {
        int v = cnt[tid];
        int s = v;
        for (int d = 1; d < LEAF; d <<= 1) {
            int t = __shfl_up(s, d, 64);
            if (tid >= d) s += t;
        }
        int excl = s - v;
        lcur[tid] = excl;
        int node = leaf * LEAF + tid;
        if (node < N_NODES) {
            off[node] = obase + excl;
            deg[node] = 1 + v;
            dinv[node] = rsqrtf((float)(1 + v));
        }
    }
    __syncthreads();
    for (int i = tid; i < len; i += 256) {
        int e = pairs2[base2 + i];
        int p = atomicAdd(&lcur[e & 63], 1);   // LDS atomic, block-local
        buf[p] = e >> 10;                      // src id
    }
    __syncthreads();
    for (int i = tid; i < len; i += 256)
        csr[obase + i] = buf[i];               // fully coalesced
}

// ---------------- GEMM1: y1 = (x @ W1) * dinv[n] ----------------

#define G1_BS 256
#define G1_NODES 128
#define G1_KT 64
#define G1_STRIDE (G1_KT + 4)   // 68 floats; 68*4=272B rows keep 16B alignment

__global__ __launch_bounds__(G1_BS) void k_gemm1(const float* __restrict__ x,
                                                 const float* __restrict__ W1,
                                                 const float* __restrict__ dinv,
                                                 float* __restrict__ y1) {
    __shared__ float xt[G1_NODES * G1_STRIDE];  // 34816 B
    __shared__ float wt[G1_KT * HID];           // 4096 B
    const int tid = threadIdx.x;
    const int nl = tid >> 2;   // node slot 0..63
    const int cg = tid & 3;    // channel group (4 ch each)
    const int node_base = blockIdx.x * G1_NODES;

    float4 acc0 = {0.f, 0.f, 0.f, 0.f};
    float4 acc1 = {0.f, 0.f, 0.f, 0.f};

    for (int kt = 0; kt < IN_CH; kt += G1_KT) {
        __syncthreads();
        for (int j = 0; j < 8; ++j) {
            int f4 = j * G1_BS + tid;
            int r = f4 >> 4;
            int c4 = f4 & 15;
            int gr = node_base + r;
            float4 v = {0.f, 0.f, 0.f, 0.f};
            if (gr < N_NODES)
                v = *(const float4*)(x + (size_t)gr * IN_CH + kt + c4 * 4);
            *(float4*)(xt + r * G1_STRIDE + c4 * 4) = v;
        }
        {
            int r = tid >> 2;
            int c4 = tid & 3;
            *(float4*)(wt + r * HID + c4 * 4) =
                *(const float4*)(W1 + (size_t)(kt + r) * HID + c4 * 4);
        }
        __syncthreads();

        for (int kk = 0; kk < G1_KT; kk += 4) {
            float4 x0 = *(const float4*)(xt + nl * G1_STRIDE + kk);
            float4 x1 = *(const float4*)(xt + (nl + 64) * G1_STRIDE + kk);
            float4 w0 = *(const float4*)(wt + (kk + 0) * HID + cg * 4);
            float4 w1 = *(const float4*)(wt + (kk + 1) * HID + cg * 4);
            float4 w2 = *(const float4*)(wt + (kk + 2) * HID + cg * 4);
            float4 w3 = *(const float4*)(wt + (kk + 3) * HID + cg * 4);
            acc0 = f4fma(x0.x, w0, acc0); acc0 = f4fma(x0.y, w1, acc0);
            acc0 = f4fma(x0.z, w2, acc0); acc0 = f4fma(x0.w, w3, acc0);
            acc1 = f4fma(x1.x, w0, acc1); acc1 = f4fma(x1.y, w1, acc1);
            acc1 = f4fma(x1.z, w2, acc1); acc1 = f4fma(x1.w, w3, acc1);
        }
    }

    int n0 = node_base + nl;
    int n1 = n0 + 64;
    if (n0 < N_NODES) {
        float dv = dinv[n0];
        float4 o = {acc0.x * dv, acc0.y * dv, acc0.z * dv, acc0.w * dv};
        *(float4*)(y1 + (size_t)n0 * HID + cg * 4) = o;
    }
    if (n1 < N_NODES) {
        float dv = dinv[n1];
        float4 o = {acc1.x * dv, acc1.y * dv, acc1.z * dv, acc1.w * dv};
        *(float4*)(y1 + (size_t)n1 * HID + cg * 4) = o;
    }
}

// ---------------- layer1: 4 threads/node, float4 gathers ----------------

__global__ __launch_bounds__(256) void k_layer1(const float* __restrict__ y1,
                                                const int* __restrict__ off,
                                                const int* __restrict__ deg,
                                                const int* __restrict__ csr,
                                                const float* __restrict__ dinv,
                                                const float* __restrict__ b1,
                                                float* __restrict__ y2) {
    int t = blockIdx.x * blockDim.x + threadIdx.x;
    int n = t >> 2;
    int cg = t & 3;
    if (n >= N_NODES) return;
    int base = off[n];
    int cnt = deg[n] - 1;
    float4 a0 = {0,0,0,0}, a1 = {0,0,0,0}, a2 = {0,0,0,0}, a3 = {0,0,0,0};
    int p = 0;
    for (; p + 4 <= cnt; p += 4) {
        int s0 = csr[base + p + 0];
        int s1 = csr[base + p + 1];
        int s2 = csr[base + p + 2];
        int s3 = csr[base + p + 3];
        a0 = f4add(a0, *(const float4*)(y1 + (size_t)s0 * HID + cg * 4));
        a1 = f4add(a1, *(const float4*)(y1 + (size_t)s1 * HID + cg * 4));
        a2 = f4add(a2, *(const float4*)(y1 + (size_t)s2 * HID + cg * 4));
        a3 = f4add(a3, *(const float4*)(y1 + (size_t)s3 * HID + cg * 4));
    }
    for (; p < cnt; ++p)
        a0 = f4add(a0, *(const float4*)(y1 + (size_t)csr[base + p] * HID + cg * 4));
    float4 acc = f4add(f4add(a0, a1), f4add(a2, a3));
    float dv = dinv[n];
    float4 self = *(const float4*)(y1 + (size_t)n * HID + cg * 4);
    float4 b = ((const float4*)b1)[cg];
    float4 h;
    h.x = fmaxf(dv * (acc.x + self.x) + b.x, 0.f) * dv;
    h.y = fmaxf(dv * (acc.y + self.y) + b.y, 0.f) * dv;
    h.z = fmaxf(dv * (acc.z + self.z) + b.z, 0.f) * dv;
    h.w = fmaxf(dv * (acc.w + self.w) + b.w, 0.f) * dv;
    *(float4*)(y2 + (size_t)n * HID + cg * 4) = h;
}

// ---------------- layer2: 4 threads/node gather + fused GEMM2 ----------------

__global__ __launch_bounds__(256) void k_layer2(const float* __restrict__ y2,
                                                const int* __restrict__ off,
                                                const int* __restrict__ deg,
                                                const int* __restrict__ csr,
                                                const float* __restrict__ dinv,
                                                const float* __restrict__ W2,
                                                const float* __restrict__ b2,
                                                float* __restrict__ out) {
    __shared__ float w2[HID * OUT_CH];  // 4 KB
    __shared__ float bs[OUT_CH];
    int tid = threadIdx.x;
    for (int j = tid; j < HID * OUT_CH; j += 256) w2[j] = W2[j];
    if (tid < OUT_CH) bs[tid] = b2[tid];
    __syncthreads();

    int t = blockIdx.x * blockDim.x + tid;
    int n = t >> 2;
    int cg = t & 3;
    if (n >= N_NODES) return;
    int base = off[n];
    int cnt = deg[n] - 1;
    float4 a0 = {0,0,0,0}, a1 = {0,0,0,0}, a2 = {0,0,0,0}, a3 = {0,0,0,0};
    int p = 0;
    for (; p + 4 <= cnt; p += 4) {
        int s0 = csr[base + p + 0];
        int s1 = csr[base + p + 1];
        int s2 = csr[base + p + 2];
        int s3 = csr[base + p + 3];
        a0 = f4add(a0, *(const float4*)(y2 + (size_t)s0 * HID + cg * 4));
        a1 = f4add(a1, *(const float4*)(y2 + (size_t)s1 * HID + cg * 4));
        a2 = f4add(a2, *(const float4*)(y2 + (size_t)s2 * HID + cg * 4));
        a3 = f4add(a3, *(const float4*)(y2 + (size_t)s3 * HID + cg * 4));
    }
    for (; p < cnt; ++p)
        a0 = f4add(a0, *(const float4*)(y2 + (size_t)csr[base + p] * HID + cg * 4));
    float4 acc = f4add(f4add(a0, a1), f4add(a2, a3));
    float dv = dinv[n];
    float4 self = *(const float4*)(y2 + (size_t)n * HID + cg * 4);
    float4 z4 = {dv * (acc.x + self.x), dv * (acc.y + self.y),
                 dv * (acc.z + self.z), dv * (acc.w + self.w)};

    // exchange z across the 4 lanes of this node (lanes (lane&~3)+j)
    int lane = tid & 63;
    int lbase = lane & ~3;
    float z[16];
    for (int j = 0; j < 4; ++j) {
        z[j * 4 + 0] = __shfl(z4.x, lbase + j, 64);
        z[j * 4 + 1] = __shfl(z4.y, lbase + j, 64);
        z[j * 4 + 2] = __shfl(z4.z, lbase + j, 64);
        z[j * 4 + 3] = __shfl(z4.w, lbase + j, 64);
    }

    // this thread computes out channels cg*16 .. cg*16+15
    float4 o0 = ((const float4*)bs)[cg * 4 + 0];
    float4 o1 = ((const float4*)bs)[cg * 4 + 1];
    float4 o2 = ((const float4*)bs)[cg * 4 + 2];
    float4 o3 = ((const float4*)bs)[cg * 4 + 3];
    for (int cc = 0; cc < HID; ++cc) {
        const float* wr = w2 + cc * OUT_CH + cg * 16;
        float zz = z[cc];
        o0 = f4fma(zz, *(const float4*)(wr + 0), o0);
        o1 = f4fma(zz, *(const float4*)(wr + 4), o1);
        o2 = f4fma(zz, *(const float4*)(wr + 8), o2);
        o3 = f4fma(zz, *(const float4*)(wr + 12), o3);
    }
    float* orow = out + (size_t)n * OUT_CH + cg * 16;
    *(float4*)(orow + 0) = o0;
    *(float4*)(orow + 4) = o1;
    *(float4*)(orow + 8) = o2;
    *(float4*)(orow + 12) = o3;
}

// ---------------- launch ----------------

extern "C" void kernel_launch(void* const* d_in, const int* in_sizes, int n_in,
                              void* d_out, int out_size, void* d_ws, size_t ws_size,
                              hipStream_t stream) {
    const float* x  = (const float*)d_in[0];
    const int*   ei = (const int*)d_in[1];
    const float* W1 = (const float*)d_in[2];
    const float* b1 = (const float*)d_in[3];
    const float* W2 = (const float*)d_in[4];
    const float* b2 = (const float*)d_in[5];
    float* out = (float*)d_out;

    const int* src = ei;            // edge_index[0]
    const int* dst = ei + N_EDGES;  // edge_index[1]

    char* w = (char*)d_ws;
    const size_t SN = 409600;  // per-N-array slot
    int*   deg      = (int*)(w);
    float* dinv     = (float*)(w + SN);
    int*   off      = (int*)(w + 2 * SN);
    int*   bcur1    = (int*)(w + 3 * SN);               // 392 B
    int*   bcur2    = (int*)(w + 3 * SN + 8192);        // 6.3 KB
    int*   leafoff  = (int*)(w + 3 * SN + 16384);       // 6.3 KB
    // regB: pairs1 (13.65 MB) during binning, then csr (12.8 MB)
    char*  regB     = w + 4 * SN;
    int*   pairs1   = (int*)regB;
    int*   csr      = (int*)regB;                       // overlay: pairs1 dead after bin2
    // regC: pairs2 (16.06 MB) during sort, then y1/y2 (12.8 MB)
    char*  regC     = regB + (size_t)NB1 * CAP1 * 4;
    int*   pairs2   = (int*)regC;
    float* y1       = (float*)regC;                     // overlay: pairs2 dead after scatter2
    float* y2       = (float*)(regC + 6553600);
    // total ws use: ~31.4 MB

    k_init_bcur<<<(NLEAF_SLOTS + 255) / 256, 256, 0, stream>>>(bcur1, bcur2);
    k_bin1<<<BIN1_BLOCKS, 256, 0, stream>>>(src, dst, pairs1, bcur1);
    k_bin2<<<NB1 * BIN2_SPLIT, 256, 0, stream>>>(pairs1, bcur1, pairs2, bcur2);
    k_leafscan<<<1, 256, 0, stream>>>(bcur2, leafoff);
    k_scatter2<<<NLEAF, 256, 0, stream>>>(pairs2, bcur2, leafoff, off, deg, dinv, csr);
    k_gemm1<<<(N_NODES + G1_NODES - 1) / G1_NODES, G1_BS, 0, stream>>>(x, W1, dinv, y1);
    k_layer1<<<(N_NODES * 4 + 255) / 256, 256, 0, stream>>>(y1, off, deg, csr, dinv, b1, y2);
    k_layer2<<<(N_NODES * 4 + 255) / 256, 256, 0, stream>>>(y2, off, deg, csr, dinv, W2, b2, out);
}